// Round 10
// baseline (246.915 us; speedup 1.0000x reference)
//
#include <hip/hip_runtime.h>

typedef _Float16 hh;
typedef _Float16 h2  __attribute__((ext_vector_type(2)));
typedef _Float16 v4h __attribute__((ext_vector_type(4)));
typedef _Float16 v8h __attribute__((ext_vector_type(8)));
typedef float v4f    __attribute__((ext_vector_type(4)));
typedef unsigned short u16;

#define T_STEPS 36
#define FEAT 9
#define HID 64
#define BT 32
// sIn row (halves, stride 264 = 132 words; 132*{0..7} mod 32 = {0,4,..,28}
// distinct -> b128 A-frag reads conflict-free (rows r/r+8 alias 2-way = free)):
//   parity0 block @0:   [c_c 0..8 | m 9..17 | h 18..81 | 1 @82 | 0 @83..95]
//   parity1 block @96:  same layout +96 (bias one @178)
//   dA @192..200 | 0 @201 | dB @202..210 | 0 @211 | 1 @212 | 0 @213..231
//   ALPHA window @232: [1 @232 | gx(t) 233..241 | m(t) 242..250 | 0 ..263]
#define SIN_STR 264
// packed per-element row (halves): x 0..8 | m 9..17 | xh 18..26 | alpha 27..35
#define PK_STR 40

__device__ __forceinline__ float fast_exp2(float x) {
#if __has_builtin(__builtin_amdgcn_exp2f)
  return __builtin_amdgcn_exp2f(x);
#else
  return exp2f(x);
#endif
}
__device__ __forceinline__ float fast_rcp(float x) {
#if __has_builtin(__builtin_amdgcn_rcpf)
  return __builtin_amdgcn_rcpf(x);
#else
  return 1.f / x;
#endif
}
__device__ __forceinline__ float sigmoid_fast(float x) {
  return fast_rcp(1.f + fast_exp2(x * -1.442695041f));
}
__device__ __forceinline__ float tanh_fast(float x) {
  return 1.f - 2.f * fast_rcp(1.f + fast_exp2(x * 2.885390082f));
}
__device__ __forceinline__ float fdot2(h2 a, h2 b, float c) {
#if __has_builtin(__builtin_amdgcn_fdot2)
  return __builtin_amdgcn_fdot2(a, b, c, false);
#else
  return c + (float)a[0] * (float)b[0] + (float)a[1] * (float)b[1];
#endif
}
__device__ __forceinline__ h2 mkh2(hh a, hh b) { h2 r; r[0] = a; r[1] = b; return r; }
__device__ __forceinline__ v4f mfma16(v8h a, v8h b, v4f c) {
  return __builtin_amdgcn_mfma_f32_16x16x32_f16(a, b, c, 0, 0, 0);
}

// ---------------- fallback kernel 0: zero ws denom slots + loss slot -------
__global__ void zero_ws(float* __restrict__ ws, float* __restrict__ out) {
  int tid = threadIdx.x;
  if (tid < T_STEPS) ws[tid] = 0.f;
  if (tid == 0) out[0] = 0.f;
}

// ---- fallback kernel 1: denom via global atomics (old path) ----
__global__ __launch_bounds__(256) void denom_kernel(const float* __restrict__ masks,
                                                    float* __restrict__ ws) {
  __shared__ float red[T_STEPS];
  const int tid = threadIdx.x;
  if (tid < T_STEPS) red[tid] = 0.f;
  __syncthreads();
  const int idx = blockIdx.x * 256 + tid;
  const int t0 = (idx % 9) * 4;
  const float4* p = (const float4*)masks + (size_t)idx * 9;
  float acc[4] = {0.f, 0.f, 0.f, 0.f};
#pragma unroll
  for (int c = 0; c < 9; ++c) {
    float4 v = p[c];
    acc[(4 * c) / 9]     += v.x;
    acc[(4 * c + 1) / 9] += v.y;
    acc[(4 * c + 2) / 9] += v.z;
    acc[(4 * c + 3) / 9] += v.w;
  }
#pragma unroll
  for (int j = 0; j < 4; ++j) atomicAdd(&red[t0 + j], acc[j]);
  __syncthreads();
  if (tid < T_STEPS) atomicAdd(&ws[tid], red[tid]);
}

// ---- kernel 1a: per-block denom partials, NO global atomics (R7, proven) --
__global__ __launch_bounds__(256) void denom_part(const float* __restrict__ masks,
                                                  float* __restrict__ ws) {
  __shared__ float red[T_STEPS];
  const int tid = threadIdx.x;
  if (tid < T_STEPS) red[tid] = 0.f;
  __syncthreads();
  const int idx = blockIdx.x * 256 + tid;
  const int t0 = (idx % 9) * 4;
  const float4* p = (const float4*)masks + (size_t)idx * 9;
  float acc[4] = {0.f, 0.f, 0.f, 0.f};
#pragma unroll
  for (int c = 0; c < 9; ++c) {
    float4 v = p[c];
    acc[(4 * c) / 9]     += v.x;
    acc[(4 * c + 1) / 9] += v.y;
    acc[(4 * c + 2) / 9] += v.z;
    acc[(4 * c + 3) / 9] += v.w;
  }
#pragma unroll
  for (int j = 0; j < 4; ++j) atomicAdd(&red[t0 + j], acc[j]);   // LDS only
  __syncthreads();
  if (tid < T_STEPS) ws[64 + blockIdx.x * T_STEPS + tid] = red[tid];
}

// ---- kernel 1b: final reduce, writes ws[t], zeroes out[0] (R7, proven) ----
__global__ __launch_bounds__(576) void denom_final(float* __restrict__ ws,
                                                   float* __restrict__ out,
                                                   int nblocks) {
  __shared__ float red[576];
  const int tid = threadIdx.x;
  const int t = tid >> 4;
  const int l = tid & 15;
  float s = 0.f;
  for (int b = l; b < nblocks; b += 16) s += ws[64 + b * T_STEPS + t];
  red[tid] = s;
  __syncthreads();
  if (l < 8) red[tid] += red[tid + 8];
  __syncthreads();
  if (l < 4) red[tid] += red[tid + 4];
  __syncthreads();
  if (l < 2) red[tid] += red[tid + 2];
  __syncthreads();
  if (l == 0) ws[t] = red[tid] + red[tid + 1];
  if (tid == 0) out[0] = 0.f;
}

// Raw barrier: LDS ordering only; global loads/stores stay in flight.
#define BARX() asm volatile("s_waitcnt lgkmcnt(0)\n\ts_barrier" ::: "memory")

// One RITS timestep, 2 barriers (R9 structure + gates K-split):
//  Phase A: x_h MFMA + alpha MFMA (sPk writes) -> gamma(t+1) MFMA -> gates
//           PARTIAL MFMAs for kt=1,2 (read ONLY the h-region of the parity
//           block, published at B(t-1) -- independent of this step's P2) ->
//           wave-local fence -> P2 scalar.
//  Phase B: gates FINISH (kt=0 only: 2 ds_reads + 8 MFMAs) + LSTM + publish h
//           + loader commits + issue next-step global loads.
//  Post-barrier-1 critical path shrinks from 24 MFMA + 6 reads to 8 + 2.
#define RITS_STEP(t, pxC,pmC,pdC,pxCb,pmCb,pdCb, pxN,pmN,pdN,pxNb,pmNb,pdNb)   \
  {                                                                            \
    const float inv_den = fast_rcp(denom[(t)] + 1e-5f);                        \
    const int pb = ((t) & 1) * 96;                                             \
    v4f gacc[2];                                                               \
    v4f gAcc[2][4];   /* gates accumulators: partial in A, finished in B */    \
    /* ---- wave-local x_h: tile mtw (redundant with pair wave), own rows */   \
    {                                                                          \
      v4f xacc = {0.f, 0.f, 0.f, 0.f};                                         \
      _Pragma("unroll")                                                        \
      for (int kt = 0; kt < 3; ++kt) {                                         \
        v8h a_ = *(const v8h*)&sIn[(mtw * 16 + nlo) * SIN_STR + pb +           \
                                   kt * 32 + q * 8];                           \
        xacc = mfma16(a_, bH[kt], xacc);                                       \
      }                                                                        \
      if ((q >> 1) == (wid & 1) && nlo < 9) {                                  \
        _Pragma("unroll")                                                      \
        for (int r = 0; r < 4; ++r)                                            \
          sPk[(mtw * 16 + q * 4 + r) * PK_STR + 18 + nlo] = (hh)xacc[r];       \
      }                                                                        \
    }                                                                          \
    /* ---- wave-local alpha(t) MFMA: window @232, tile mtw, own 8 rows */     \
    {                                                                          \
      v8h a_ = *(const v8h*)&sIn[(mtw * 16 + nlo) * SIN_STR + 232 + q * 8];    \
      v4f z4 = {0.f, 0.f, 0.f, 0.f};                                           \
      v4f aacc = mfma16(a_, bAl, z4);                                          \
      if ((q >> 1) == (wid & 1) && nlo < 9) {                                  \
        _Pragma("unroll")                                                      \
        for (int r = 0; r < 4; ++r)                                            \
          sPk[(mtw * 16 + q * 4 + r) * PK_STR + 27 + nlo] = (hh)aacc[r];       \
      }                                                                        \
    }                                                                          \
    /* ---- gamma(t+1)-arg MFMA (all rows, both tiles; used in Phase B) */     \
    {                                                                          \
      const int sel = ((t) + 1) & 1;                                           \
      const int awin = 176 + sel * 24;                                         \
      _Pragma("unroll")                                                        \
      for (int mt = 0; mt < 2; ++mt) {                                         \
        v8h a_ = *(const v8h*)&sIn[(mt * 16 + nlo) * SIN_STR + awin + q * 8];  \
        v4f z4 = {0.f, 0.f, 0.f, 0.f};                                         \
        gacc[mt] = sel ? mfma16(a_, bGamB, z4) : mfma16(a_, bGamA, z4);        \
      }                                                                        \
    }                                                                          \
    /* ---- gates PARTIAL: kt=1,2 read pure-h K region (ready since B(t-1)) */ \
    {                                                                          \
      _Pragma("unroll")                                                        \
      for (int mt = 0; mt < 2; ++mt) {                                         \
        v8h a1 = *(const v8h*)&sIn[(mt * 16 + nlo) * SIN_STR + pb + 32 + q * 8]; \
        v8h a2 = *(const v8h*)&sIn[(mt * 16 + nlo) * SIN_STR + pb + 64 + q * 8]; \
        _Pragma("unroll")                                                      \
        for (int p = 0; p < 4; ++p) {                                          \
          v4f z4 = {0.f, 0.f, 0.f, 0.f};                                       \
          gAcc[mt][p] = mfma16(a2, bG[p][2], mfma16(a1, bG[p][1], z4));        \
        }                                                                      \
      }                                                                        \
    }                                                                          \
    /* wave-local producer->consumer fence (no cross-wave dependency) */       \
    asm volatile("s_waitcnt lgkmcnt(0)" ::: "memory");                         \
    /* ==== P2: wave-local — x_c, z, c_h, c_c, loss (alpha precomputed) */     \
    {                                                                          \
      const int pk = eP * PK_STR;                                              \
      float x_f  = (float)sPk[pk + fqw];                                       \
      float m_f  = (float)sPk[pk + 9 + fqw];                                   \
      float xh_f = (float)sPk[pk + 18 + fqw];                                  \
      float a1   = (float)sPk[pk + 27 + fqw];                                  \
      v8h r0 = *(const v8h*)&sPk[pk];                                          \
      v8h r1 = *(const v8h*)&sPk[pk + 8];                                      \
      v8h r2 = *(const v8h*)&sPk[pk + 16];                                     \
      v8h r3 = *(const v8h*)&sPk[pk + 24];                                     \
      hh xxh[9] = {r0[0],r0[1],r0[2],r0[3],r0[4],r0[5],r0[6],r0[7],r1[0]};     \
      hh mmh[9] = {r1[1],r1[2],r1[3],r1[4],r1[5],r1[6],r1[7],r2[0],r2[1]};     \
      hh xhh[9] = {r2[2],r2[3],r2[4],r2[5],r2[6],r2[7],r3[0],r3[1],r3[2]};     \
      hh xch[10];                                                              \
      _Pragma("unroll")                                                        \
      for (int f = 0; f < 9; ++f) {                                            \
        u16 mb = __builtin_bit_cast(u16, mmh[f]);                              \
        xch[f] = mb ? xxh[f] : xhh[f];                                         \
      }                                                                        \
      xch[9] = (hh)0.f;                                                        \
      h2 xc2[5] = {mkh2(xch[0],xch[1]), mkh2(xch[2],xch[3]),                   \
                   mkh2(xch[4],xch[5]), mkh2(xch[6],xch[7]),                   \
                   mkh2(xch[8],xch[9])};                                       \
      float z1a = bf1, z1b = 0.f;                                              \
      z1a = fdot2(wf1[0], xc2[0], z1a); z1b = fdot2(wf1[1], xc2[1], z1b);      \
      z1a = fdot2(wf1[2], xc2[2], z1a); z1b = fdot2(wf1[3], xc2[3], z1b);      \
      z1a = fdot2(wf1[4], xc2[4], z1a);                                        \
      float z1 = z1a + z1b;                                                    \
      float ch1 = xh_f + a1 * (z1 - xh_f);                                     \
      bool obs1 = (m_f != 0.f);                                                \
      float cc1 = obs1 ? x_f : ch1;                                            \
      float lterm = obs1 ? (fabsf(x_f - xh_f) + fabsf(x_f - z1) +              \
                            fabsf(x_f - ch1)) : 0.f;                           \
      sIn[eP * SIN_STR + pb + fqw] = (hh)cc1;                                  \
      sIn[eP * SIN_STR + pb + 9 + fqw] = (hh)m_f;                              \
      op1[0] = cc1;                                                            \
      if (fqw == 7) {                                                          \
        float a2 = (float)sPk[pk + 27 + 8];                                    \
        float z2a = bf2, z2b = 0.f;                                            \
        z2a = fdot2(wf2[0], xc2[0], z2a); z2b = fdot2(wf2[1], xc2[1], z2b);    \
        z2a = fdot2(wf2[2], xc2[2], z2a); z2b = fdot2(wf2[3], xc2[3], z2b);    \
        z2a = fdot2(wf2[4], xc2[4], z2a);                                      \
        float z2 = z2a + z2b;                                                  \
        float x8 = (float)xxh[8], m8 = (float)mmh[8], xh8 = (float)xhh[8];     \
        float ch2 = xh8 + a2 * (z2 - xh8);                                     \
        bool obs2 = (m8 != 0.f);                                               \
        float cc2 = obs2 ? x8 : ch2;                                           \
        lterm += obs2 ? (fabsf(x8 - xh8) + fabsf(x8 - z2) +                    \
                         fabsf(x8 - ch2)) : 0.f;                               \
        sIn[eP * SIN_STR + pb + 8] = (hh)cc2;                                  \
        sIn[eP * SIN_STR + pb + 17] = mmh[8];                                  \
        op1[1] = cc2;                                                          \
      }                                                                        \
      loss_acc += lterm * inv_den;                                             \
      op1 += FEAT;                                                             \
    }                                                                          \
    BARX();                                                                    \
    /* ==== Phase B: issue next loads, FINISH gates (kt=0), LSTM, publish */   \
    {                                                                          \
      const bool ldN = ((t) + 2 < T_STEPS);                                    \
      const bool ldD = ((t) + 3 < T_STEPS);                                    \
      if (ldN) {                                                               \
        size_t offn = (size_t)(b0 + e1) * (T_STEPS * FEAT) +                   \
                      ((t) + 2) * FEAT + f1;                                   \
        pxN = values[offn]; pmN = masks[offn];                                 \
        if (tid < 32) {                                                        \
          size_t offn2 = (size_t)(b0 + e2g) * (T_STEPS * FEAT) +               \
                         ((t) + 2) * FEAT + f2g;                               \
          pxNb = values[offn2]; pmNb = masks[offn2];                           \
        }                                                                      \
      }                                                                        \
      if (ldD) {                                                               \
        size_t offd = (size_t)(b0 + e1) * (T_STEPS * FEAT) +                   \
                      ((t) + 3) * FEAT + f1;                                   \
        pdN = deltas[offd];                                                    \
        if (tid < 32) {                                                        \
          size_t offd2 = (size_t)(b0 + e2g) * (T_STEPS * FEAT) +               \
                         ((t) + 3) * FEAT + f2g;                               \
          pdNb = deltas[offd2];                                                \
        }                                                                      \
      }                                                                        \
      const int pub = (((t) + 1) & 1) * 96;                                    \
      v8h af0[2];                                                              \
      _Pragma("unroll")                                                        \
      for (int mt = 0; mt < 2; ++mt)                                           \
        af0[mt] = *(const v8h*)&sIn[(mt * 16 + nlo) * SIN_STR + pb + q * 8];   \
      _Pragma("unroll")                                                        \
      for (int mt = 0; mt < 2; ++mt)                                           \
        _Pragma("unroll")                                                      \
        for (int p = 0; p < 4; ++p)                                            \
          gAcc[mt][p] = mfma16(af0[mt], bG[p][0], gAcc[mt][p]);                \
      _Pragma("unroll")                                                        \
      for (int mt = 0; mt < 2; ++mt) {                                         \
        _Pragma("unroll")                                                      \
        for (int r = 0; r < 4; ++r) {                                          \
          float ig = sigmoid_fast(gAcc[mt][0][r]);                             \
          float fg = sigmoid_fast(gAcc[mt][1][r]);                             \
          float gg = tanh_fast(gAcc[mt][2][r]);                                \
          float og = sigmoid_fast(gAcc[mt][3][r]);                             \
          float cn = fg * c_s[mt * 4 + r] + ig * gg;                           \
          c_s[mt * 4 + r] = cn;                                                \
          float hn = og * tanh_fast(cn);                                       \
          float gam = fast_exp2(fmaxf(gacc[mt][r], 0.f) * -1.442695041f);      \
          sIn[(mt * 16 + q * 4 + r) * SIN_STR + pub + 18 + j_col] =            \
              (hh)(hn * gam);                                                  \
        }                                                                      \
      }                                                                        \
      if ((t) + 1 < T_STEPS) {                                                 \
        sPk[e1 * PK_STR + f1] = (hh)pxC;                                       \
        sPk[e1 * PK_STR + 9 + f1] = (hh)pmC;                                   \
        sIn[e1 * SIN_STR + 233 + f1] =                                         \
            (hh)fast_exp2(fmaxf(dH * wgx1 + bgx1, 0.f) * -1.442695041f);       \
        sIn[e1 * SIN_STR + 242 + f1] = (hh)pmC;                                \
        if (tid < 32) {                                                        \
          sPk[e2g * PK_STR + f2g] = (hh)pxCb;                                  \
          sPk[e2g * PK_STR + 9 + f2g] = (hh)pmCb;                              \
          sIn[e2g * SIN_STR + 233 + f2g] =                                     \
              (hh)fast_exp2(fmaxf(dHb * wgx2 + bgx2, 0.f) * -1.442695041f);    \
          sIn[e2g * SIN_STR + 242 + f2g] = (hh)pmCb;                           \
        }                                                                      \
      }                                                                        \
      if ((t) + 2 < T_STEPS) {                                                 \
        const int sb = 192 + ((t) & 1) * 10;                                   \
        sIn[e1 * SIN_STR + sb + f1] = (hh)pdC;                                 \
        if (tid < 32) sIn[e2g * SIN_STR + sb + f2g] = (hh)pdCb;                \
      }                                                                        \
      dH = pdC; dHb = pdCb;                                                    \
    }                                                                          \
    BARX();                                                                    \
  }

// ---------------- kernel 2: the full RITS scan ------------------------------
__global__ __launch_bounds__(256, 2) void rits_kernel(
    const float* __restrict__ values, const float* __restrict__ masks,
    const float* __restrict__ deltas,
    const float* __restrict__ W_gh, const float* __restrict__ b_gh,
    const float* __restrict__ W_gx, const float* __restrict__ b_gx,
    const float* __restrict__ W_hist, const float* __restrict__ b_hist,
    const float* __restrict__ W_feat, const float* __restrict__ b_feat,
    const float* __restrict__ W_comb, const float* __restrict__ b_comb,
    const float* __restrict__ W_ih, const float* __restrict__ W_hh,
    const float* __restrict__ b_ih, const float* __restrict__ b_hh,
    const float* __restrict__ denom, float* __restrict__ out) {

  __shared__ __align__(16) hh sIn[BT * SIN_STR];   // 16896 B
  __shared__ __align__(16) hh sPk[BT * PK_STR];    //  2560 B
  __shared__ float sRed[256];

  const int tid = threadIdx.x;
  const int lane = tid & 63;
  const int wid = tid >> 6;
  const int q = lane >> 4;
  const int nlo = lane & 15;
  const int b0 = blockIdx.x * BT;
  const int j_col = 16 * wid + nlo;
  const int mtw = wid >> 1;          // 16-row tile containing this wave's elems

  // ---- persistent register B-fragments (k = q*8+jj relative to window) ----
  v8h bG[4][3];        // gates: window = parity block, k0..17 Wih, 18..81 Whh, 82 bias
#pragma unroll
  for (int p = 0; p < 4; ++p)
#pragma unroll
    for (int kt = 0; kt < 3; ++kt) {
      int n = 64 * p + j_col;
      v8h r;
#pragma unroll
      for (int jj = 0; jj < 8; ++jj) {
        int k = kt * 32 + q * 8 + jj;
        float v = 0.f;
        if (k < 18)       v = W_ih[n * 18 + k];
        else if (k < 82)  v = W_hh[n * 64 + (k - 18)];
        else if (k == 82) v = b_ih[n] + b_hh[n];
        r[jj] = (hh)v;
      }
      bG[p][kt] = r;
    }
  v8h bH[3];           // x_h: cols nlo<9, k 18..81 Whist, 82 bias
#pragma unroll
  for (int kt = 0; kt < 3; ++kt) {
    v8h r;
#pragma unroll
    for (int jj = 0; jj < 8; ++jj) {
      int k = kt * 32 + q * 8 + jj;
      float v = 0.f;
      if (nlo < 9) {
        if (k >= 18 && k < 82) v = W_hist[nlo * 64 + (k - 18)];
        else if (k == 82)      v = b_hist[nlo];
      }
      r[jj] = (hh)v;
    }
    bH[kt] = r;
  }
  // gamma_h windows: A @176 (k2='1'@178 -> b_gh, k16..24 = dA); B @200 (k2..10 = dB, k12='1'@212)
  v8h bGamA, bGamB;
  {
    int n = j_col;
    v8h ra, rb;
#pragma unroll
    for (int jj = 0; jj < 8; ++jj) {
      int k = q * 8 + jj;
      float va = 0.f, vb = 0.f;
      if (k == 2) va = b_gh[n];
      else if (k >= 16 && k < 25) va = W_gh[n * 9 + (k - 16)];
      if (k >= 2 && k < 11) vb = W_gh[n * 9 + (k - 2)];
      else if (k == 12) vb = b_gh[n];
      ra[jj] = (hh)va; rb[jj] = (hh)vb;
    }
    bGamA = ra; bGamB = rb;
  }
  // alpha window fragment: k0 -> b_comb (hits the '1' @232), k1..9 -> W_comb
  // gx-part, k10..18 -> W_comb m-part; cols nlo<9.
  v8h bAl;
  {
    v8h r;
#pragma unroll
    for (int jj = 0; jj < 8; ++jj) {
      int k = q * 8 + jj;
      float v = 0.f;
      if (nlo < 9) {
        if (k == 0)       v = b_comb[nlo];
        else if (k < 10)  v = W_comb[nlo * 18 + (k - 1)];
        else if (k < 19)  v = W_comb[nlo * 18 + 9 + (k - 10)];
      }
      r[jj] = (hh)v;
    }
    bAl = r;
  }

  // ---- per-lane P2 weights (runtime row fq baked into registers) ----
  const int eP = tid >> 3, fqw = tid & 7;
  h2 wf1[5], wf2[5];
  float bf1 = b_feat[fqw], bf2 = b_feat[8];
#pragma unroll
  for (int j = 0; j < 5; ++j) {
    int i0 = 2 * j, i1 = 2 * j + 1;
    hh a0 = (hh)((i0 == fqw) ? 0.f : W_feat[fqw * 9 + i0]);
    hh a1 = (hh)((i1 < 9) ? ((i1 == fqw) ? 0.f : W_feat[fqw * 9 + i1]) : 0.f);
    wf1[j] = mkh2(a0, a1);
    hh c0 = (hh)((i0 == 8) ? 0.f : W_feat[8 * 9 + i0]);
    hh c1 = (hh)((i1 < 9) ? W_feat[8 * 9 + i1] : 0.f);
    wf2[j] = mkh2(c0, c1);
  }

  // ---- loader thread mapping + per-loader gamma_x weights ----
  const int e1 = tid / 9, f1 = tid - 9 * e1;
  const int e2g = (tid + 256) / 9, f2g = (tid + 256) - 9 * e2g;
  const float wgx1 = W_gx[f1 * 9 + f1], bgx1 = b_gx[f1];
  float wgx2 = 0.f, bgx2 = 0.f;
  if (tid < 32) { wgx2 = W_gx[f2g * 9 + f2g]; bgx2 = b_gx[f2g]; }

  // ---- per-thread output pointer (advances FEAT floats per step) ----
  float* op1 = out + 1 + (size_t)(b0 + eP) * (T_STEPS * FEAT) + fqw;

  // ---- LDS init ----
  for (int i = tid; i < BT * SIN_STR; i += 256) sIn[i] = (hh)0.f;
  __syncthreads();
  if (tid < BT) {
    sIn[tid * SIN_STR + 82] = (hh)1.f;
    sIn[tid * SIN_STR + 178] = (hh)1.f;
    sIn[tid * SIN_STR + 212] = (hh)1.f;
    sIn[tid * SIN_STR + 232] = (hh)1.f;   // alpha-window bias one
  }
  // prefetch register sets (A/B alternate per step parity)
  float pA_x = 0.f, pA_m = 0.f, pA_d = 0.f, pA_xb = 0.f, pA_mb = 0.f, pA_db = 0.f;
  float pB_x = 0.f, pB_m = 0.f, pB_d = 0.f, pB_xb = 0.f, pB_mb = 0.f, pB_db = 0.f;
  float dH = 0.f, dHb = 0.f;    // deltas(t+1) for the gx commit at PhaseB(t)
  {
    size_t off = (size_t)(b0 + e1) * (T_STEPS * FEAT) + f1;
    float d0 = deltas[off];
    float m0 = masks[off];
    sPk[e1 * PK_STR + f1] = (hh)values[off];
    sPk[e1 * PK_STR + 9 + f1] = (hh)m0;
    sIn[e1 * SIN_STR + 233 + f1] =
        (hh)fast_exp2(fmaxf(d0 * wgx1 + bgx1, 0.f) * -1.442695041f);
    sIn[e1 * SIN_STR + 242 + f1] = (hh)m0;
    float d1 = deltas[off + FEAT];
    dH = d1;
    sIn[e1 * SIN_STR + 202 + f1] = (hh)d1;    // d(1) -> dB (parity 1)
    pA_x = values[off + FEAT]; pA_m = masks[off + FEAT];   // t=1 data
    pA_d = deltas[off + 2 * FEAT];                         // d(2)
    if (tid < 32) {
      size_t off2 = (size_t)(b0 + e2g) * (T_STEPS * FEAT) + f2g;
      float d0b = deltas[off2];
      float m0b = masks[off2];
      sPk[e2g * PK_STR + f2g] = (hh)values[off2];
      sPk[e2g * PK_STR + 9 + f2g] = (hh)m0b;
      sIn[e2g * SIN_STR + 233 + f2g] =
          (hh)fast_exp2(fmaxf(d0b * wgx2 + bgx2, 0.f) * -1.442695041f);
      sIn[e2g * SIN_STR + 242 + f2g] = (hh)m0b;
      float d1b = deltas[off2 + FEAT];
      dHb = d1b;
      sIn[e2g * SIN_STR + 202 + f2g] = (hh)d1b;
      pA_xb = values[off2 + FEAT]; pA_mb = masks[off2 + FEAT];
      pA_db = deltas[off2 + 2 * FEAT];
    }
  }
  __syncthreads();

  float c_s[8];
#pragma unroll
  for (int i = 0; i < 8; ++i) c_s[i] = 0.f;
  float loss_acc = 0.f;

  for (int t = 0; t < T_STEPS; t += 2) {
    RITS_STEP(t,     pA_x, pA_m, pA_d, pA_xb, pA_mb, pA_db,
                     pB_x, pB_m, pB_d, pB_xb, pB_mb, pB_db);
    RITS_STEP(t + 1, pB_x, pB_m, pB_d, pB_xb, pB_mb, pB_db,
                     pA_x, pA_m, pA_d, pA_xb, pA_mb, pA_db);
  }

  // ---- loss reduction ----
  sRed[tid] = loss_acc;
  __syncthreads();
  for (int k = 128; k > 0; k >>= 1) {
    if (tid < k) sRed[tid] += sRed[tid + k];
    __syncthreads();
  }
  if (tid == 0) atomicAdd(out, sRed[0] * (1.f / (float)T_STEPS));
}

extern "C" void kernel_launch(void* const* d_in, const int* in_sizes, int n_in,
                              void* d_out, int out_size, void* d_ws, size_t ws_size,
                              hipStream_t stream) {
  const float* values = (const float*)d_in[0];
  const float* masks  = (const float*)d_in[1];
  const float* deltas = (const float*)d_in[2];
  const float* W_gh   = (const float*)d_in[3];
  const float* b_gh   = (const float*)d_in[4];
  const float* W_gx   = (const float*)d_in[5];
  const float* b_gx   = (const float*)d_in[6];
  const float* W_hist = (const float*)d_in[7];
  const float* b_hist = (const float*)d_in[8];
  const float* W_feat = (const float*)d_in[9];
  const float* b_feat = (const float*)d_in[10];
  const float* W_comb = (const float*)d_in[11];
  const float* b_comb = (const float*)d_in[12];
  const float* W_ih   = (const float*)d_in[13];
  const float* W_hh   = (const float*)d_in[14];
  const float* b_ih   = (const float*)d_in[15];
  const float* b_hh   = (const float*)d_in[16];

  float* out = (float*)d_out;
  float* ws  = (float*)d_ws;
  int B = in_sizes[0] / (T_STEPS * FEAT);
  int nb1 = (B * 9) / 256;

  size_t need = (size_t)(64 + (size_t)nb1 * T_STEPS) * sizeof(float);
  if (ws_size >= need) {
    denom_part<<<nb1, 256, 0, stream>>>(masks, ws);
    denom_final<<<1, 576, 0, stream>>>(ws, out, nb1);
  } else {
    zero_ws<<<1, 64, 0, stream>>>(ws, out);
    denom_kernel<<<nb1, 256, 0, stream>>>(masks, ws);
  }
  rits_kernel<<<B / BT, 256, 0, stream>>>(values, masks, deltas,
                                          W_gh, b_gh, W_gx, b_gx,
                                          W_hist, b_hist, W_feat, b_feat,
                                          W_comb, b_comb, W_ih, W_hh,
                                          b_ih, b_hh, ws, out);
}